// Round 1
// baseline (873.984 us; speedup 1.0000x reference)
//
#include <hip/hip_runtime.h>
#include <hip/hip_bf16.h>

// Fused: out = swish(swish(groupnorm(x@W + b)) * mw)
// M=65536, K=1024, N=1024, G=32 (group width 32 channels)
//
// Kernel 1: W fp32 [K][N] -> Wt bf16 [N][K], with per-row 16B-chunk XOR swizzle
//           (chunk c -> c ^ ((n>>1)&3) within each 32-k tile) so the GEMM's
//           B-fragment ds_read_b128 is bank-conflict-free from a LINEAR
//           global_load_lds destination (pre-swizzled-source pattern).
// Kernel 2: 128x128x32 bf16-MFMA GEMM.
//           - XCD-bijective block remap: the 8 column-blocks sharing one x
//             row-panel run adjacent on ONE XCD -> panel fetched once per L2.
//           - A path: no LDS. Each lane loads its own MFMA A-fragment rows
//             directly from global (fp32), packed-converts to bf16, with a
//             one-K-step register prefetch hidden under the MFMA phase.
//           - B path: global_load_lds (16B) into double-buffered LDS,
//             one __syncthreads per K-step.
//           - Epilogue: bias + GroupNorm + swish*mw*swish in-register.

typedef __attribute__((ext_vector_type(8))) short short8;
typedef __attribute__((ext_vector_type(4))) float floatx4;

#define K_DIM 1024
#define N_DIM 1024
#define BM 128
#define BN 128
#define BK 32

__device__ __forceinline__ unsigned short f2bf(float f) {
    // round-to-nearest-even fp32 -> bf16
    unsigned int u = __float_as_uint(f);
    u += 0x7FFFu + ((u >> 16) & 1u);
    return (unsigned short)(u >> 16);
}

// packed fp32x8 -> bf16x8 (RNE) via __float22bfloat162_rn (v_cvt_pk_bf16_f32)
__device__ __forceinline__ short8 cvt8(floatx4 a, floatx4 b) {
    union { __hip_bfloat162 h[4]; short8 s; } u;
    u.h[0] = __float22bfloat162_rn(float2{a[0], a[1]});
    u.h[1] = __float22bfloat162_rn(float2{a[2], a[3]});
    u.h[2] = __float22bfloat162_rn(float2{b[0], b[1]});
    u.h[3] = __float22bfloat162_rn(float2{b[2], b[3]});
    return u.s;
}

// ---- Kernel 1: transpose + convert + chunk-swizzle W -> Wt (bf16, [N][K]) ----
__global__ __launch_bounds__(256) void prep_w_kernel(const float* __restrict__ W,
                                                     unsigned short* __restrict__ Wt) {
    __shared__ float s[32][33];
    const int tx = threadIdx.x & 31;
    const int ty = threadIdx.x >> 5;        // 0..7
    const int kt = (blockIdx.x & 31) << 5;  // k tile origin
    const int nt = (blockIdx.x >> 5) << 5;  // n tile origin
    #pragma unroll
    for (int i = 0; i < 4; ++i)
        s[ty + i * 8][tx] = W[(size_t)(kt + ty + i * 8) * N_DIM + nt + tx];
    __syncthreads();
    #pragma unroll
    for (int i = 0; i < 4; ++i) {
        const int n = nt + ty + i * 8;
        const int sw = (n >> 1) & 3;                    // bank-swizzle selector
        const int col = (((tx >> 3) ^ sw) << 3) | (tx & 7);  // permute 8-elem chunks
        Wt[(size_t)n * K_DIM + kt + col] = f2bf(s[tx][ty + i * 8]);
    }
}

// ---- Kernel 2: fused GEMM + bias + GroupNorm + swish*mw*swish ----
__global__ __launch_bounds__(256, 3) void fused_kernel(const float* __restrict__ x,
                                                       const unsigned short* __restrict__ Wt,
                                                       const float* __restrict__ bias,
                                                       const float* __restrict__ mulw,
                                                       float* __restrict__ out) {
    __shared__ unsigned short Bs[2 * BN * BK];   // 16 KB, double-buffered

    const int tid  = threadIdx.x;
    const int lane = tid & 63;
    const int wid  = tid >> 6;     // 4 waves
    const int wm   = wid >> 1;     // 2x2 wave grid
    const int wn   = wid & 1;
    const int q    = lane >> 4;    // quad (k-phase for A/B frags; row-phase for C)
    const int ln   = lane & 15;

    // XCD-bijective remap: dispatcher round-robins blockIdx across 8 XCDs.
    // Give each XCD 64 full row-panels; within an XCD, column index is fastest
    // so the 8 blocks sharing one x row-panel are temporally adjacent on ONE L2.
    const int bid  = blockIdx.x;
    const int xcd  = bid & 7;
    const int lid  = bid >> 3;             // 0..511
    const int bRow = xcd * 64 + (lid >> 3);
    const int bCol = lid & 7;
    const int m0 = bRow * BM;
    const int n0 = bCol * BN;

    floatx4 acc[4][4];
    #pragma unroll
    for (int i = 0; i < 4; ++i)
        #pragma unroll
        for (int j = 0; j < 4; ++j)
            acc[i][j] = (floatx4){0.f, 0.f, 0.f, 0.f};

    // B staging via global_load_lds: per wave 2 issues of 16 rows x 32 k (1 KB each)
    const int bnr = (lane >> 2);          // row-within-16 (4 lanes/row)
    const int bkc = (lane & 3) << 3;      // 8-elem k chunk
    const unsigned short* wtp = Wt + (size_t)(n0 + wid * 32 + bnr) * K_DIM + bkc;

    // A fragment base: lane (q,ln) of wave wm owns rows wm*64 + im*16 + ln,
    // k-chunk q*8 .. q*8+7 (two fp32x4 loads per row).
    const float* aptr = x + (size_t)(m0 + wm * 64 + ln) * K_DIM + (q << 3);

    // B fragment read base (XOR-swizzled chunk select; sw depends only on ln)
    const int swb = (ln >> 1) & 3;
    const unsigned short* brd = Bs + (size_t)(wn * 64 + ln) * BK + ((q ^ swb) << 3);

    // ---- prologue: A(0) into regs, B(0) into buf0 ----
    floatx4 apre[4][2];
    #pragma unroll
    for (int im = 0; im < 4; ++im) {
        apre[im][0] = *(const floatx4*)(aptr + (size_t)im * 16 * K_DIM);
        apre[im][1] = *(const floatx4*)(aptr + (size_t)im * 16 * K_DIM + 4);
    }
    #pragma unroll
    for (int j = 0; j < 2; ++j) {
        __builtin_amdgcn_global_load_lds(
            (const __attribute__((address_space(1))) unsigned int*)(wtp + (size_t)j * 16 * K_DIM),
            (__attribute__((address_space(3))) unsigned int*)(Bs + (wid * 2 + j) * 512),
            16, 0, 0);
    }
    __syncthreads();

    int curOff = 0;
    for (int k0 = 0; k0 < K_DIM; k0 += BK) {
        const int knext = (k0 + BK) & (K_DIM - 1);   // wrap: last-iter prefetch is benign
        const int nxtOff = curOff ^ (BN * BK);

        // issue next B tile -> other buffer (in flight across this whole iteration)
        #pragma unroll
        for (int j = 0; j < 2; ++j) {
            __builtin_amdgcn_global_load_lds(
                (const __attribute__((address_space(1))) unsigned int*)(wtp + (size_t)j * 16 * K_DIM + knext),
                (__attribute__((address_space(3))) unsigned int*)(Bs + nxtOff + (wid * 2 + j) * 512),
                16, 0, 0);
        }

        // convert current A regs -> bf16 frags, then prefetch next A (no barrier dep)
        short8 af[4];
        #pragma unroll
        for (int im = 0; im < 4; ++im)
            af[im] = cvt8(apre[im][0], apre[im][1]);
        #pragma unroll
        for (int im = 0; im < 4; ++im) {
            apre[im][0] = *(const floatx4*)(aptr + (size_t)im * 16 * K_DIM + knext);
            apre[im][1] = *(const floatx4*)(aptr + (size_t)im * 16 * K_DIM + knext + 4);
        }

        short8 bfv[4];
        #pragma unroll
        for (int in = 0; in < 4; ++in)
            bfv[in] = *(const short8*)(brd + curOff + (size_t)in * 16 * BK);

        #pragma unroll
        for (int im = 0; im < 4; ++im)
            #pragma unroll
            for (int in = 0; in < 4; ++in)
                acc[im][in] = __builtin_amdgcn_mfma_f32_16x16x32_bf16(
                    af[im], bfv[in], acc[im][in], 0, 0, 0);

        __syncthreads();   // drains vmcnt: next B tile + A prefetch landed
        curOff = nxtOff;
    }

    // ---- epilogue: bias + GroupNorm(32-wide groups) + swish * mw + swish ----
    // C/D layout: col = ln, row = q*4 + r. Wave covers cols wn*64 + in*16 + ln.
    float bv[4], wv[4];
    #pragma unroll
    for (int in = 0; in < 4; ++in) {
        int col = n0 + wn * 64 + in * 16 + ln;
        bv[in] = bias[col];
        wv[in] = mulw[col];
    }
    #pragma unroll
    for (int im = 0; im < 4; ++im)
        #pragma unroll
        for (int in = 0; in < 4; ++in)
            #pragma unroll
            for (int r = 0; r < 4; ++r)
                acc[im][in][r] += bv[in];

    const float inv32 = 1.0f / 32.0f;
    #pragma unroll
    for (int im = 0; im < 4; ++im) {
        const int rowb = m0 + wm * 64 + im * 16 + q * 4;
        #pragma unroll
        for (int p = 0; p < 2; ++p) {   // group p covers tiles in=2p, 2p+1 (32 cols)
            const int i0 = 2 * p, i1 = 2 * p + 1;
            float mean[4], rstd[4];
            #pragma unroll
            for (int r = 0; r < 4; ++r) {
                float y0 = acc[im][i0][r], y1 = acc[im][i1][r];
                float s1 = y0 + y1;
                float s2 = y0 * y0 + y1 * y1;
                #pragma unroll
                for (int d = 1; d < 16; d <<= 1) {   // butterfly within 16-lane quad
                    s1 += __shfl_xor(s1, d, 64);
                    s2 += __shfl_xor(s2, d, 64);
                }
                float mn = s1 * inv32;
                float var = s2 * inv32 - mn * mn;
                mean[r] = mn;
                rstd[r] = rsqrtf(var + 1e-5f);
            }
            #pragma unroll
            for (int ii = i0; ii <= i1; ++ii) {
                const int col = n0 + wn * 64 + ii * 16 + ln;
                const float w = wv[ii];
                #pragma unroll
                for (int r = 0; r < 4; ++r) {
                    float y   = acc[im][ii][r];
                    float nrm = (y - mean[r]) * rstd[r];
                    float s   = nrm / (1.0f + __expf(-nrm));
                    float m2  = s * w;
                    float o   = m2 / (1.0f + __expf(-m2));
                    out[(size_t)(rowb + r) * N_DIM + col] = o;
                }
            }
        }
    }
}

extern "C" void kernel_launch(void* const* d_in, const int* in_sizes, int n_in,
                              void* d_out, int out_size, void* d_ws, size_t ws_size,
                              hipStream_t stream) {
    const float* x  = (const float*)d_in[0];
    const float* W  = (const float*)d_in[1];
    const float* b  = (const float*)d_in[2];
    const float* mw = (const float*)d_in[3];
    float* out = (float*)d_out;
    unsigned short* Wt = (unsigned short*)d_ws;  // 1024*1024 bf16 = 2 MB

    prep_w_kernel<<<1024, 256, 0, stream>>>(W, Wt);

    const int M = in_sizes[0] / K_DIM;            // 65536
    const int grid = (M / BM) * (N_DIM / BN);     // 512 * 8 = 4096
    fused_kernel<<<grid, 256, 0, stream>>>(x, Wt, b, mw, out);
}

// Round 2
// 754.662 us; speedup vs baseline: 1.1581x; 1.1581x over previous
//
#include <hip/hip_runtime.h>
#include <hip/hip_bf16.h>

// Fused: out = swish(swish(groupnorm(x@W + b)) * mw)
// M=65536, K=1024, N=1024, G=32 (group width 32 channels)
//
// Kernel 1: W fp32 [K][N] -> Wt bf16 [N][K], with per-row 16B-chunk XOR swizzle
//           (chunk c -> c ^ ((n>>1)&3) within each 32-k tile) so the GEMM's
//           B-fragment ds_read_b128 is bank-conflict-free from a LINEAR
//           global_load_lds destination (pre-swizzled-source pattern).
// Kernel 2: 128x128x32 bf16-MFMA GEMM, m97-style double-buffered pipeline:
//           - XCD-bijective block remap (panel sharers adjacent on one L2).
//           - B: global_load_lds (16B) into double-buffered LDS.
//           - A: coalesced fp32 loads -> v_cvt_pk_bf16_f32 -> ds_write into
//             double-buffered padded LDS (SA=40 -> conflict-free b128).
//           - ONE __syncthreads per K-step; next-tile loads issued before
//             current-tile MFMA so latency hides under compute.
//           - Epilogue: bias + GroupNorm + swish*mw*swish in-register.

typedef __attribute__((ext_vector_type(8))) short short8;
typedef __attribute__((ext_vector_type(4))) float floatx4;

#define K_DIM 1024
#define N_DIM 1024
#define BM 128
#define BN 128
#define BK 32
#define SA 40   // padded As row stride in bf16 elems (80 B -> uniform bank spread)

__device__ __forceinline__ unsigned short f2bf(float f) {
    // round-to-nearest-even fp32 -> bf16
    unsigned int u = __float_as_uint(f);
    u += 0x7FFFu + ((u >> 16) & 1u);
    return (unsigned short)(u >> 16);
}

// packed fp32x8 -> bf16x8 (RNE) via __float22bfloat162_rn (v_cvt_pk_bf16_f32)
__device__ __forceinline__ short8 cvt8(floatx4 a, floatx4 b) {
    union { __hip_bfloat162 h[4]; short8 s; } u;
    u.h[0] = __float22bfloat162_rn(float2{a[0], a[1]});
    u.h[1] = __float22bfloat162_rn(float2{a[2], a[3]});
    u.h[2] = __float22bfloat162_rn(float2{b[0], b[1]});
    u.h[3] = __float22bfloat162_rn(float2{b[2], b[3]});
    return u.s;
}

// ---- Kernel 1: transpose + convert + chunk-swizzle W -> Wt (bf16, [N][K]) ----
__global__ __launch_bounds__(256) void prep_w_kernel(const float* __restrict__ W,
                                                     unsigned short* __restrict__ Wt) {
    __shared__ float s[32][33];
    const int tx = threadIdx.x & 31;
    const int ty = threadIdx.x >> 5;        // 0..7
    const int kt = (blockIdx.x & 31) << 5;  // k tile origin
    const int nt = (blockIdx.x >> 5) << 5;  // n tile origin
    #pragma unroll
    for (int i = 0; i < 4; ++i)
        s[ty + i * 8][tx] = W[(size_t)(kt + ty + i * 8) * N_DIM + nt + tx];
    __syncthreads();
    #pragma unroll
    for (int i = 0; i < 4; ++i) {
        const int n = nt + ty + i * 8;
        const int sw = (n >> 1) & 3;                         // bank-swizzle selector
        const int col = (((tx >> 3) ^ sw) << 3) | (tx & 7);  // permute 8-elem chunks
        Wt[(size_t)n * K_DIM + kt + col] = f2bf(s[tx][ty + i * 8]);
    }
}

// ---- Kernel 2: fused GEMM + bias + GroupNorm + swish*mw*swish ----
__global__ __launch_bounds__(256, 3) void fused_kernel(const float* __restrict__ x,
                                                       const unsigned short* __restrict__ Wt,
                                                       const float* __restrict__ bias,
                                                       const float* __restrict__ mulw,
                                                       float* __restrict__ out) {
    __shared__ unsigned short As[2 * BM * SA];   // 20480 B, padded, double-buffered
    __shared__ unsigned short Bs[2 * BN * BK];   // 16384 B, linear, double-buffered

    const int tid  = threadIdx.x;
    const int lane = tid & 63;
    const int wid  = tid >> 6;     // 4 waves
    const int wm   = wid >> 1;     // 2x2 wave grid
    const int wn   = wid & 1;
    const int q    = lane >> 4;    // quad (k-phase for A/B frags; row-phase for C)
    const int ln   = lane & 15;

    // XCD-bijective remap: 8 blocks sharing an x row-panel run adjacent on ONE XCD.
    const int bid  = blockIdx.x;
    const int xcd  = bid & 7;
    const int lid  = bid >> 3;             // 0..511
    const int bRow = xcd * 64 + (lid >> 3);
    const int bCol = lid & 7;
    const int m0 = bRow * BM;
    const int n0 = bCol * BN;

    floatx4 acc[4][4];
    #pragma unroll
    for (int i = 0; i < 4; ++i)
        #pragma unroll
        for (int j = 0; j < 4; ++j)
            acc[i][j] = (floatx4){0.f, 0.f, 0.f, 0.f};

    // A staging: thread t handles As row t/2, 16 contiguous k at col (t&1)*16
    const int arow = tid >> 1;
    const int acol = (tid & 1) << 4;
    const float* xptr = x + (size_t)(m0 + arow) * K_DIM + acol;
    unsigned short* aw = As + arow * SA + acol;

    // B staging via global_load_lds: per wave 2 issues of 16 rows x 32 k (1 KB each)
    const int bnr = (lane >> 2);          // row-within-16 (4 lanes/row)
    const int bkc = (lane & 3) << 3;      // 8-elem k chunk
    const unsigned short* wtp = Wt + (size_t)(n0 + wid * 32 + bnr) * K_DIM + bkc;

    // fragment read bases (buffer offset added in-loop)
    const unsigned short* ard = As + (wm * 64 + ln) * SA + q * 8;
    const int swb = (ln >> 1) & 3;
    const unsigned short* brd = Bs + (wn * 64 + ln) * BK + ((q ^ swb) << 3);

    // ---- prologue: stage k=0 into buffer 0 ----
    {
        #pragma unroll
        for (int j = 0; j < 2; ++j) {
            __builtin_amdgcn_global_load_lds(
                (const __attribute__((address_space(1))) unsigned int*)(wtp + (size_t)j * 16 * K_DIM),
                (__attribute__((address_space(3))) unsigned int*)(Bs + (wid * 2 + j) * 512),
                16, 0, 0);
        }
        floatx4 f0 = *(const floatx4*)(xptr);
        floatx4 f1 = *(const floatx4*)(xptr + 4);
        floatx4 f2 = *(const floatx4*)(xptr + 8);
        floatx4 f3 = *(const floatx4*)(xptr + 12);
        *(short8*)aw       = cvt8(f0, f1);
        *(short8*)(aw + 8) = cvt8(f2, f3);
    }
    __syncthreads();

    int cur = 0;
    for (int k0 = 0; k0 < K_DIM; k0 += BK) {
        const int knext = (k0 + BK) & (K_DIM - 1);   // wrap: last prefetch benign
        const int nxt = cur ^ 1;

        // next-A fp32 loads (coalesced, 64B/lane) -- in flight across MFMA phase
        floatx4 g0 = *(const floatx4*)(xptr + knext);
        floatx4 g1 = *(const floatx4*)(xptr + knext + 4);
        floatx4 g2 = *(const floatx4*)(xptr + knext + 8);
        floatx4 g3 = *(const floatx4*)(xptr + knext + 12);

        // next-B tile -> other LDS buffer (in flight across MFMA phase)
        #pragma unroll
        for (int j = 0; j < 2; ++j) {
            __builtin_amdgcn_global_load_lds(
                (const __attribute__((address_space(1))) unsigned int*)(wtp + (size_t)j * 16 * K_DIM + knext),
                (__attribute__((address_space(3))) unsigned int*)(Bs + nxt * (BN * BK) + (wid * 2 + j) * 512),
                16, 0, 0);
        }

        // current-tile fragments + MFMA
        short8 af[4], bfv[4];
        #pragma unroll
        for (int im = 0; im < 4; ++im)
            af[im] = *(const short8*)(ard + cur * (BM * SA) + im * 16 * SA);
        #pragma unroll
        for (int in = 0; in < 4; ++in)
            bfv[in] = *(const short8*)(brd + cur * (BN * BK) + in * 16 * BK);
        #pragma unroll
        for (int im = 0; im < 4; ++im)
            #pragma unroll
            for (int in = 0; in < 4; ++in)
                acc[im][in] = __builtin_amdgcn_mfma_f32_16x16x32_bf16(
                    af[im], bfv[in], acc[im][in], 0, 0, 0);

        // convert + write next-A into other buffer (A loads have had MFMA to land)
        *(short8*)(aw + nxt * (BM * SA))     = cvt8(g0, g1);
        *(short8*)(aw + nxt * (BM * SA) + 8) = cvt8(g2, g3);

        __syncthreads();
        cur = nxt;
    }

    // ---- epilogue: bias + GroupNorm(32-wide groups) + swish * mw + swish ----
    // C/D layout: col = ln, row = q*4 + r. Wave covers cols wn*64 + in*16 + ln.
    float bv[4], wv[4];
    #pragma unroll
    for (int in = 0; in < 4; ++in) {
        int col = n0 + wn * 64 + in * 16 + ln;
        bv[in] = bias[col];
        wv[in] = mulw[col];
    }
    #pragma unroll
    for (int im = 0; im < 4; ++im)
        #pragma unroll
        for (int in = 0; in < 4; ++in)
            #pragma unroll
            for (int r = 0; r < 4; ++r)
                acc[im][in][r] += bv[in];

    const float inv32 = 1.0f / 32.0f;
    #pragma unroll
    for (int im = 0; im < 4; ++im) {
        const int rowb = m0 + wm * 64 + im * 16 + q * 4;
        #pragma unroll
        for (int p = 0; p < 2; ++p) {   // group p covers tiles in=2p, 2p+1 (32 cols)
            const int i0 = 2 * p, i1 = 2 * p + 1;
            float mean[4], rstd[4];
            #pragma unroll
            for (int r = 0; r < 4; ++r) {
                float y0 = acc[im][i0][r], y1 = acc[im][i1][r];
                float s1 = y0 + y1;
                float s2 = y0 * y0 + y1 * y1;
                #pragma unroll
                for (int d = 1; d < 16; d <<= 1) {   // butterfly within 16-lane quad
                    s1 += __shfl_xor(s1, d, 64);
                    s2 += __shfl_xor(s2, d, 64);
                }
                float mn = s1 * inv32;
                float var = s2 * inv32 - mn * mn;
                mean[r] = mn;
                rstd[r] = rsqrtf(var + 1e-5f);
            }
            #pragma unroll
            for (int ii = i0; ii <= i1; ++ii) {
                const int col = n0 + wn * 64 + ii * 16 + ln;
                const float w = wv[ii];
                #pragma unroll
                for (int r = 0; r < 4; ++r) {
                    float y   = acc[im][ii][r];
                    float nrm = (y - mean[r]) * rstd[r];
                    float s   = nrm / (1.0f + __expf(-nrm));
                    float m2  = s * w;
                    float o   = m2 / (1.0f + __expf(-m2));
                    out[(size_t)(rowb + r) * N_DIM + col] = o;
                }
            }
        }
    }
}

extern "C" void kernel_launch(void* const* d_in, const int* in_sizes, int n_in,
                              void* d_out, int out_size, void* d_ws, size_t ws_size,
                              hipStream_t stream) {
    const float* x  = (const float*)d_in[0];
    const float* W  = (const float*)d_in[1];
    const float* b  = (const float*)d_in[2];
    const float* mw = (const float*)d_in[3];
    float* out = (float*)d_out;
    unsigned short* Wt = (unsigned short*)d_ws;  // 1024*1024 bf16 = 2 MB

    prep_w_kernel<<<1024, 256, 0, stream>>>(W, Wt);

    const int M = in_sizes[0] / K_DIM;            // 65536
    const int grid = (M / BM) * (N_DIM / BN);     // 512 * 8 = 4096
    fused_kernel<<<grid, 256, 0, stream>>>(x, Wt, b, mw, out);
}